// Round 21
// baseline (196.902 us; speedup 1.0000x reference)
//
#include <hip/hip_runtime.h>

#define T_ 30
#define H_ 41
#define WD_ 2048
#define NSEC 9
#define FM 50
#define WP 502
#define THRESH 23.0f
#define POOLED_SIZE (NSEC * T_ * FM * WP)   // 6,777,000
#define MARGIN 0.125f                       // >> realistic f16 max error (~0.02)
#define NFRAG 18432                         // 9 sec * 64 fm * 32 tap-octets
#define TTB 3                               // tt values per block

typedef _Float16 half8 __attribute__((ext_vector_type(8)));
typedef _Float16 half4v __attribute__((ext_vector_type(4)));
typedef float f32x4 __attribute__((ext_vector_type(4)));

__device__ __forceinline__ unsigned short f16_bits(float f) {
    union { _Float16 h; unsigned short s; } u;
    u.h = (_Float16)f;
    return u.s;
}

// ---------------- prep: W -> MFMA-ready f16 fragments in ws ---------------
__global__ __launch_bounds__(256) void prep_kernel(
    const float* __restrict__ Wg, int* __restrict__ wsi,
    uint4* __restrict__ wfh)
{
    const int gid = blockIdx.x * 256 + threadIdx.x;
    if (gid < NSEC) wsi[gid] = 0x7fffffff;
    if (gid >= NFRAG) return;
    const int blk = gid & 31;
    const int fm  = (gid >> 5) & 63;
    const int sec = gid >> 11;
    const int t0  = blk * 8;
    const bool valid = (t0 < 240) && (fm < FM);
    const float* wp = Wg + ((size_t)sec * FM + (valid ? fm : 0)) * 240 + (valid ? t0 : 0);
    float4 wa = *reinterpret_cast<const float4*>(wp);
    float4 wb = *reinterpret_cast<const float4*>(wp + 4);
    float f[8] = {wa.x, wa.y, wa.z, wa.w, wb.x, wb.y, wb.z, wb.w};
    unsigned hh[4];
#pragma unroll
    for (int i = 0; i < 4; ++i) {
        unsigned h0 = f16_bits(valid ? f[2 * i] : 0.f);
        unsigned h1 = f16_bits(valid ? f[2 * i + 1] : 0.f);
        hh[i] = (h1 << 16) | h0;
    }
    wfh[gid] = *reinterpret_cast<uint4*>(hh);
}

// ---------------- Kernel A: f16 MFMA conv + fire/pool/argmin --------------
// R30 = R27 per-tt body wrapped in a persistent TTB=3 loop (grid 4320->1440).
// Occupancy model (R23/R24/R17/R28/R29): static cap = m69 halving law
// (VGPR<=32: 32 waves/CU; 33-64: 16; 65-128: 8); achieved ~= 75% of cap.
// The 25% gap's candidate mechanism: block-transition dead time (SPI launch
// + serial staging phases, ~17 launches/CU). TTB=3 cuts transitions to 5.6
// and amortizes pA/cmask setup. Hot math per tt is byte-identical to R27
// -> absmax 0. launch_bounds(256,4) pins VGPR <= 64 (16-wave cap band).
// LDS/sred cross-iteration reuse is barrier-safe: the loop-top barrier
// orders iteration i's sred[0] read (tid0 atomicMin) before iteration
// i+1's lmask writes; staging writes only xh.
template <bool PRE>
__global__ __launch_bounds__(256, 4) void conv_pool_kernel(
    const float* __restrict__ x, const float* __restrict__ Wg,
    const uint4* __restrict__ wfh,
    float* __restrict__ out, int* __restrict__ keys)
{
    __shared__ __align__(16) unsigned short xh[4][10][192];   // 15 KB (f16)
    __shared__ int sred[256];                                  // lmask, then red

    const int b       = blockIdx.x;
    const int coltile = b & 15;
    const int ttg     = (b >> 4) % (T_ / TTB);
    const int sec     = b / (16 * (T_ / TTB));
    const int w0      = coltile * 128;     // pot-col base
    const int rowbase = 4 * sec;
    const int tid     = threadIdx.x;

    const int L    = tid & 63;
    const int j_p  = tid >> 6;       // wave id = pot row
    const int q    = L >> 4;         // quad (K-octet)
    const int n16  = L & 15;         // A: m-index; B: fm-index

    // per-kk tap geometry (tau0 = 32kk + 8q -> weight row r, col c0), swizzled
    int pA[8], pB[8];
#pragma unroll
    for (int kk = 0; kk < 8; ++kk) {
        const int t0 = 32 * kk + 8 * q;
        const int r  = t0 / 40;
        const int c0 = t0 - 40 * r;          // multiple of 8
        const int row = j_p + r;
        const int xr  = (row & 7) << 3;
        const int s   = c0 + 8 * n16;        // multiple of 8, <= 152
        pA[kk] = row * 192 + (s ^ xr);       // octet [s, s+8)
        pB[kk] = row * 192 + ((s + 8) ^ xr); // octet [s+8, s+16)
    }

    // column-validity lane masks (res-independent: pcg<=2007 for all res
    // <=> w0 + 8*(q*4+reg) <= 2000). Wave-uniform -> SGPR pairs, no VGPR.
    unsigned long long cmask[4];
#pragma unroll
    for (int reg = 0; reg < 4; ++reg)
        cmask[reg] = __ballot(w0 + 8 * (q * 4 + reg) <= 2000);

#pragma unroll 1
    for (int it = 0; it < TTB; ++it) {
        const int tt = ttg * TTB + it;
        __syncthreads();                 // order prior sred reads before reuse

        // ---- stage x: 10 rows x 176 cols -> f16, 4 shifted planes, swizzled ----
        for (int i = tid; i < 440; i += 256) {
            const int row = i / 44;
            const int c4  = i % 44;
            const int grow = (rowbase + row < H_) ? rowbase + row : H_ - 1;
            const int gc   = w0 + 4 * c4;
            float4 v;
            if (gc + 3 < WD_) {
                v = *reinterpret_cast<const float4*>(x + ((size_t)tt * H_ + grow) * WD_ + gc);
            } else {
                v.x = v.y = v.z = v.w = 0.f;
            }
            float f[4] = {v.x, v.y, v.z, v.w};
            unsigned short hq[4];
#pragma unroll
            for (int e = 0; e < 4; ++e) hq[e] = f16_bits(f[e]);
            const int xr = (row & 7) << 3;
#pragma unroll
            for (int S = 0; S < 4; ++S)
#pragma unroll
                for (int e = 0; e < 4; ++e) {
                    const int j = 4 * c4 + e - S;
                    if (j >= 0 && j < 176) xh[S][row][j ^ xr] = hq[e];
                }
        }
        __syncthreads();

        unsigned mask = 0;

#pragma unroll 1
        for (int ft = 0; ft < 4; ++ft) {
            const int fm = ft * 16 + n16;
            const unsigned long long fmmask = __ballot(fm < FM);
            half8 wh[8];
            if (PRE) {
                const int fb = (sec * 64 + ft * 16 + n16) * 32 + q;
#pragma unroll
                for (int kk = 0; kk < 8; ++kk) {
                    union { uint4 u; half8 h; } c1;
                    c1.u = wfh[fb + 4 * kk];
                    wh[kk] = c1.h;
                }
            } else {
                // fallback: in-kernel build (used only if ws too small)
#pragma unroll
                for (int kk = 0; kk < 8; ++kk) {
                    const int t0 = 32 * kk + 8 * q;
                    const bool wvalid = (t0 < 240) && (fm < FM);
                    const float* wp = Wg + (size_t)sec * FM * 240 +
                                      (size_t)(wvalid ? fm : 0) * 240 + (wvalid ? t0 : 0);
                    float4 wa = *reinterpret_cast<const float4*>(wp);
                    float4 wb = *reinterpret_cast<const float4*>(wp + 4);
                    float f[8] = {wa.x, wa.y, wa.z, wa.w, wb.x, wb.y, wb.z, wb.w};
                    union { unsigned u[4]; half8 h; } c1;
#pragma unroll
                    for (int i = 0; i < 4; ++i) {
                        unsigned h0 = f16_bits(wvalid ? f[2 * i] : 0.f);
                        unsigned h1 = f16_bits(wvalid ? f[2 * i + 1] : 0.f);
                        c1.u[i] = (h1 << 16) | h0;
                    }
                    wh[kk] = c1.h;
                }
            }

#pragma unroll 1
            for (int S = 0; S < 4; ++S) {
                const unsigned short* hb = &xh[S][0][0];

                f32x4 acc0 = {0.f, 0.f, 0.f, 0.f};   // res = S     (off 0)
                f32x4 acc1 = {0.f, 0.f, 0.f, 0.f};   // res = S + 4 (off 4)
#pragma unroll
                for (int kk = 0; kk < 8; ++kk) {
                    half8 ah0 = *reinterpret_cast<const half8*>(hb + pA[kk]);
                    half4v h1 = *reinterpret_cast<const half4v*>(hb + pB[kk]);
                    half8 hx  = __builtin_shufflevector(h1, h1, 0, 1, 2, 3, 0, 1, 2, 3);
                    half8 ah1 = __builtin_shufflevector(ah0, hx, 4, 5, 6, 7, 8, 9, 10, 11);
                    acc0 = __builtin_amdgcn_mfma_f32_16x16x32_f16(ah0, wh[kk], acc0, 0, 0, 0);
                    acc1 = __builtin_amdgcn_mfma_f32_16x16x32_f16(ah1, wh[kk], acc1, 0, 0, 0);
                }

                // ---- epilogue: 4-VALU checks; rare set-only repair ----
                auto epilogue = [&](const f32x4& acc, const int res) {
#pragma unroll
                    for (int reg = 0; reg < 4; ++reg) {
                        const float a = acc[reg];
                        const unsigned bitv = 1u << (reg * 8 + ft * 2 + (res >> 2));
                        const bool bhi = (a >= THRESH + MARGIN);
                        if (bhi) mask |= bitv;               // certain spike
                        unsigned long long bm =
                            __ballot(a > THRESH - MARGIN) & ~__ballot(bhi) &
                            fmmask & cmask[reg];
                        while (bm) {                          // rare
                            const int src = __ffsll((long long)bm) - 1;
                            bm &= bm - 1;
                            const int q_s   = src >> 4;
                            const int fm_s  = ft * 16 + (src & 15);
                            const int pcg_s = w0 + res + 8 * (q_s * 4 + reg);
                            float part = 0.f;
#pragma unroll
                            for (int k2 = 0; k2 < 4; ++k2) {
                                const int t = L + 64 * k2;
                                if (t < 240) {
                                    const int r2 = t / 40, c2 = t - 40 * r2;
                                    part = fmaf(
                                        x[((size_t)tt * H_ + rowbase + j_p + r2) * WD_ + pcg_s + c2],
                                        Wg[(size_t)sec * FM * 240 + (size_t)fm_s * 240 + t],
                                        part);
                                }
                            }
#pragma unroll
                            for (int off = 32; off; off >>= 1)
                                part += __shfl_xor(part, off);
                            if (L == src && part > THRESH)
                                mask |= bitv;                // SET-ONLY (monotone OR)
                        }
                    }
                };
                epilogue(acc0, S);
                epilogue(acc1, S + 4);
            }
        }

        unsigned* lmask = reinterpret_cast<unsigned*>(sred);
        lmask[j_p * 64 + L] = mask;
        __syncthreads();

        // ---- cross-wave OR + pooled write + fused first-spike argmin ----
        int mykey = 0x7fffffff;
        for (int e = tid; e < 2048; e += 256) {
            const int fmo = e >> 5, p = e & 31;
            const int m = p >> 1, rg = p & 1, ftc = fmo >> 4, fn = fmo & 15;
            const int lane = (m >> 2) * 16 + fn;
            const int bitpos = (m & 3) * 8 + ftc * 2 + rg;
            const unsigned bits = lmask[0 * 64 + lane] | lmask[1 * 64 + lane] |
                                  lmask[2 * 64 + lane] | lmask[3 * 64 + lane];
            const int pg = coltile * 32 + p;
            const int spk = (bits >> bitpos) & 1u;
            if (fmo < FM && pg < WP) {
                out[((size_t)(sec * T_ + tt) * FM + fmo) * WP + pg] = spk ? 1.0f : 0.0f;
                if (spk) mykey = min(mykey, fmo * WP + pg);   // section-flat idx
            }
        }
        __syncthreads();                     // protect lmask -> red reuse
        sred[tid] = mykey;
        __syncthreads();
        for (int s = 128; s > 0; s >>= 1) {
            if (tid < s) sred[tid] = min(sred[tid], sred[tid + s]);
            __syncthreads();
        }
        if (tid == 0 && sred[0] != 0x7fffffff)
            atomicMin(&keys[sec], (tt << 15) | sred[0]);
    }
}

// ---------------- init (fallback only) ----------------
__global__ void init_kernel(int* __restrict__ ws)
{
    if (threadIdx.x < NSEC) ws[threadIdx.x] = 0x7fffffff;
}

// ---------------- Kernel D: finalize winners ----------------
__global__ void finalize_kernel(const int* __restrict__ ws, float* __restrict__ out)
{
    const int i = threadIdx.x;
    if (i < NSEC) {
        const int key = ws[i];
        float feat;
        if (key == 0x7fffffff) feat = -1.0f;
        else                   feat = (float)((key & 32767) / WP);
        out[POOLED_SIZE + i] = feat;
    }
}

extern "C" void kernel_launch(void* const* d_in, const int* in_sizes, int n_in,
                              void* d_out, int out_size, void* d_ws, size_t ws_size,
                              hipStream_t stream) {
    const float* x  = (const float*)d_in[0];
    const float* Wg = (const float*)d_in[1];
    float* out = (float*)d_out;
    int*   wsi = (int*)d_ws;
    uint4* wfh = (uint4*)((char*)d_ws + 256);

    const bool pre = ws_size >= 256 + (size_t)NFRAG * 16;   // ~295 KB
    if (pre) {
        prep_kernel<<<dim3(72), dim3(256), 0, stream>>>(Wg, wsi, wfh);
        conv_pool_kernel<true><<<dim3(1440), dim3(256), 0, stream>>>(x, Wg, wfh, out, wsi);
    } else {
        init_kernel<<<dim3(1), dim3(64), 0, stream>>>(wsi);
        conv_pool_kernel<false><<<dim3(1440), dim3(256), 0, stream>>>(x, Wg, wfh, out, wsi);
    }
    finalize_kernel<<<dim3(1), dim3(16), 0, stream>>>(wsi, out);
}

// Round 22
// 166.616 us; speedup vs baseline: 1.1818x; 1.1818x over previous
//
#include <hip/hip_runtime.h>

#define T_ 30
#define H_ 41
#define WD_ 2048
#define NSEC 9
#define FM 50
#define WP 502
#define THRESH 23.0f
#define POOLED_SIZE (NSEC * T_ * FM * WP)   // 6,777,000
#define MARGIN 0.125f                       // >> realistic f16 max error (~0.02)
#define NFRAG 18432                         // 9 sec * 64 fm * 32 tap-octets

typedef _Float16 half8 __attribute__((ext_vector_type(8)));
typedef _Float16 half4v __attribute__((ext_vector_type(4)));
typedef float f32x4 __attribute__((ext_vector_type(4)));

__device__ __forceinline__ unsigned short f16_bits(float f) {
    union { _Float16 h; unsigned short s; } u;
    u.h = (_Float16)f;
    return u.s;
}

// ---------------- prep: W -> MFMA-ready f16 fragments in ws ---------------
__global__ __launch_bounds__(256) void prep_kernel(
    const float* __restrict__ Wg, int* __restrict__ wsi,
    uint4* __restrict__ wfh)
{
    const int gid = blockIdx.x * 256 + threadIdx.x;
    if (gid < NSEC) wsi[gid] = 0x7fffffff;
    if (gid >= NFRAG) return;
    const int blk = gid & 31;
    const int fm  = (gid >> 5) & 63;
    const int sec = gid >> 11;
    const int t0  = blk * 8;
    const bool valid = (t0 < 240) && (fm < FM);
    const float* wp = Wg + ((size_t)sec * FM + (valid ? fm : 0)) * 240 + (valid ? t0 : 0);
    float4 wa = *reinterpret_cast<const float4*>(wp);
    float4 wb = *reinterpret_cast<const float4*>(wp + 4);
    float f[8] = {wa.x, wa.y, wa.z, wa.w, wb.x, wb.y, wb.z, wb.w};
    unsigned hh[4];
#pragma unroll
    for (int i = 0; i < 4; ++i) {
        unsigned h0 = f16_bits(valid ? f[2 * i] : 0.f);
        unsigned h1 = f16_bits(valid ? f[2 * i + 1] : 0.f);
        hh[i] = (h1 << 16) | h0;
    }
    wfh[gid] = *reinterpret_cast<uint4*>(hh);
}

// ---------------- Kernel A: f16 MFMA conv + fire/pool/argmin --------------
// R31 = FINAL: exact R23/R27 (twice-verified best: e2e 166.99/167.05us,
// conv ~118-119.5, VGPR 64, absmax 0). Session falsification record --
// every axis measured-and-closed around this artifact: DS cut (R22 null),
// VALU cuts (R23 -5us, R24 null), MFMA chain split (R25 -2us), LDS 16-31KB
// (R14 null), VGPR cliff (R17/R21: >64 halves residency), 8-wave blocks
// (R28/R29: occupancy 75% but wall flat), VMEM-inner-loop (R16 +180us),
// worklist repair (R18 +110us), last-block fusion (R26 +110us), persistent
// TTB loop (R30 +28us). Floor = per-wave dependency latency at the
// scheduler's intrinsic ~12 waves/CU; not HBM (4%), not MFMA (25%), not
// VALU (53%). The wins that mattered: f16 single-term MFMA (R15) and
// ballot-algebra epilogue (R23).
template <bool PRE>
__global__ __launch_bounds__(256) void conv_pool_kernel(
    const float* __restrict__ x, const float* __restrict__ Wg,
    const uint4* __restrict__ wfh,
    float* __restrict__ out, int* __restrict__ keys)
{
    __shared__ __align__(16) unsigned short xh[4][10][192];   // 15 KB (f16)
    __shared__ int sred[256];                                  // lmask, then red

    const int b       = blockIdx.x;
    const int coltile = b & 15;
    const int tt      = (b >> 4) % T_;
    const int sec     = b / 480;
    const int w0      = coltile * 128;     // pot-col base
    const int rowbase = 4 * sec;
    const int tid     = threadIdx.x;

    // ---- stage x: 10 rows x 176 cols -> f16, 4 shifted planes, swizzled ----
    for (int i = tid; i < 440; i += 256) {
        const int row = i / 44;
        const int c4  = i % 44;
        const int grow = (rowbase + row < H_) ? rowbase + row : H_ - 1;
        const int gc   = w0 + 4 * c4;
        float4 v;
        if (gc + 3 < WD_) {
            v = *reinterpret_cast<const float4*>(x + ((size_t)tt * H_ + grow) * WD_ + gc);
        } else {
            v.x = v.y = v.z = v.w = 0.f;
        }
        float f[4] = {v.x, v.y, v.z, v.w};
        unsigned short hq[4];
#pragma unroll
        for (int e = 0; e < 4; ++e) hq[e] = f16_bits(f[e]);
        const int xr = (row & 7) << 3;
#pragma unroll
        for (int S = 0; S < 4; ++S)
#pragma unroll
            for (int e = 0; e < 4; ++e) {
                const int j = 4 * c4 + e - S;
                if (j >= 0 && j < 176) xh[S][row][j ^ xr] = hq[e];
            }
    }
    __syncthreads();

    const int L    = tid & 63;
    const int j_p  = tid >> 6;       // wave id = pot row
    const int q    = L >> 4;         // quad (K-octet)
    const int n16  = L & 15;         // A: m-index; B: fm-index

    // per-kk tap geometry (tau0 = 32kk + 8q -> weight row r, col c0), swizzled
    int pA[8], pB[8];
#pragma unroll
    for (int kk = 0; kk < 8; ++kk) {
        const int t0 = 32 * kk + 8 * q;
        const int r  = t0 / 40;
        const int c0 = t0 - 40 * r;          // multiple of 8
        const int row = j_p + r;
        const int xr  = (row & 7) << 3;
        const int s   = c0 + 8 * n16;        // multiple of 8, <= 152
        pA[kk] = row * 192 + (s ^ xr);       // octet [s, s+8)
        pB[kk] = row * 192 + ((s + 8) ^ xr); // octet [s+8, s+16)
    }

    // column-validity lane masks (res-independent: pcg<=2007 for all res
    // <=> w0 + 8*(q*4+reg) <= 2000). Wave-uniform -> SGPR pairs, no VGPR.
    unsigned long long cmask[4];
#pragma unroll
    for (int reg = 0; reg < 4; ++reg)
        cmask[reg] = __ballot(w0 + 8 * (q * 4 + reg) <= 2000);

    unsigned mask = 0;

#pragma unroll 1
    for (int ft = 0; ft < 4; ++ft) {
        const int fm = ft * 16 + n16;
        const unsigned long long fmmask = __ballot(fm < FM);
        half8 wh[8];
        if (PRE) {
            const int fb = (sec * 64 + ft * 16 + n16) * 32 + q;
#pragma unroll
            for (int kk = 0; kk < 8; ++kk) {
                union { uint4 u; half8 h; } c1;
                c1.u = wfh[fb + 4 * kk];
                wh[kk] = c1.h;
            }
        } else {
            // fallback: in-kernel build (used only if ws too small)
#pragma unroll
            for (int kk = 0; kk < 8; ++kk) {
                const int t0 = 32 * kk + 8 * q;
                const bool wvalid = (t0 < 240) && (fm < FM);
                const float* wp = Wg + (size_t)sec * FM * 240 +
                                  (size_t)(wvalid ? fm : 0) * 240 + (wvalid ? t0 : 0);
                float4 wa = *reinterpret_cast<const float4*>(wp);
                float4 wb = *reinterpret_cast<const float4*>(wp + 4);
                float f[8] = {wa.x, wa.y, wa.z, wa.w, wb.x, wb.y, wb.z, wb.w};
                union { unsigned u[4]; half8 h; } c1;
#pragma unroll
                for (int i = 0; i < 4; ++i) {
                    unsigned h0 = f16_bits(wvalid ? f[2 * i] : 0.f);
                    unsigned h1 = f16_bits(wvalid ? f[2 * i + 1] : 0.f);
                    c1.u[i] = (h1 << 16) | h0;
                }
                wh[kk] = c1.h;
            }
        }

#pragma unroll 1
        for (int S = 0; S < 4; ++S) {
            const unsigned short* hb = &xh[S][0][0];

            f32x4 acc0 = {0.f, 0.f, 0.f, 0.f};   // res = S     (off 0)
            f32x4 acc1 = {0.f, 0.f, 0.f, 0.f};   // res = S + 4 (off 4)
#pragma unroll
            for (int kk = 0; kk < 8; ++kk) {
                half8 ah0 = *reinterpret_cast<const half8*>(hb + pA[kk]);
                half4v h1 = *reinterpret_cast<const half4v*>(hb + pB[kk]);
                half8 hx  = __builtin_shufflevector(h1, h1, 0, 1, 2, 3, 0, 1, 2, 3);
                half8 ah1 = __builtin_shufflevector(ah0, hx, 4, 5, 6, 7, 8, 9, 10, 11);
                acc0 = __builtin_amdgcn_mfma_f32_16x16x32_f16(ah0, wh[kk], acc0, 0, 0, 0);
                acc1 = __builtin_amdgcn_mfma_f32_16x16x32_f16(ah1, wh[kk], acc1, 0, 0, 0);
            }

            // ---- epilogue: 4-VALU checks; rare set-only repair ----
            auto epilogue = [&](const f32x4& acc, const int res) {
#pragma unroll
                for (int reg = 0; reg < 4; ++reg) {
                    const float a = acc[reg];
                    const unsigned bitv = 1u << (reg * 8 + ft * 2 + (res >> 2));
                    const bool bhi = (a >= THRESH + MARGIN);
                    if (bhi) mask |= bitv;               // certain spike
                    unsigned long long bm =
                        __ballot(a > THRESH - MARGIN) & ~__ballot(bhi) &
                        fmmask & cmask[reg];
                    while (bm) {                          // rare
                        const int src = __ffsll((long long)bm) - 1;
                        bm &= bm - 1;
                        const int q_s   = src >> 4;
                        const int fm_s  = ft * 16 + (src & 15);
                        const int pcg_s = w0 + res + 8 * (q_s * 4 + reg);
                        float part = 0.f;
#pragma unroll
                        for (int k2 = 0; k2 < 4; ++k2) {
                            const int t = L + 64 * k2;
                            if (t < 240) {
                                const int r2 = t / 40, c2 = t - 40 * r2;
                                part = fmaf(
                                    x[((size_t)tt * H_ + rowbase + j_p + r2) * WD_ + pcg_s + c2],
                                    Wg[(size_t)sec * FM * 240 + (size_t)fm_s * 240 + t],
                                    part);
                            }
                        }
#pragma unroll
                        for (int off = 32; off; off >>= 1)
                            part += __shfl_xor(part, off);
                        if (L == src && part > THRESH)
                            mask |= bitv;                // SET-ONLY (monotone OR)
                    }
                }
            };
            epilogue(acc0, S);
            epilogue(acc1, S + 4);
        }
    }

    unsigned* lmask = reinterpret_cast<unsigned*>(sred);
    lmask[j_p * 64 + L] = mask;
    __syncthreads();

    // ---- cross-wave OR + pooled write + fused first-spike argmin ----
    int mykey = 0x7fffffff;
    for (int e = tid; e < 2048; e += 256) {
        const int fmo = e >> 5, p = e & 31;
        const int m = p >> 1, rg = p & 1, ftc = fmo >> 4, fn = fmo & 15;
        const int lane = (m >> 2) * 16 + fn;
        const int bitpos = (m & 3) * 8 + ftc * 2 + rg;
        const unsigned bits = lmask[0 * 64 + lane] | lmask[1 * 64 + lane] |
                              lmask[2 * 64 + lane] | lmask[3 * 64 + lane];
        const int pg = coltile * 32 + p;
        const int spk = (bits >> bitpos) & 1u;
        if (fmo < FM && pg < WP) {
            out[((size_t)(sec * T_ + tt) * FM + fmo) * WP + pg] = spk ? 1.0f : 0.0f;
            if (spk) mykey = min(mykey, fmo * WP + pg);   // section-flat idx
        }
    }
    __syncthreads();                     // protect lmask -> red reuse
    sred[tid] = mykey;
    __syncthreads();
    for (int s = 128; s > 0; s >>= 1) {
        if (tid < s) sred[tid] = min(sred[tid], sred[tid + s]);
        __syncthreads();
    }
    if (tid == 0 && sred[0] != 0x7fffffff)
        atomicMin(&keys[sec], (tt << 15) | sred[0]);
}

// ---------------- init (fallback only) ----------------
__global__ void init_kernel(int* __restrict__ ws)
{
    if (threadIdx.x < NSEC) ws[threadIdx.x] = 0x7fffffff;
}

// ---------------- Kernel D: finalize winners ----------------
__global__ void finalize_kernel(const int* __restrict__ ws, float* __restrict__ out)
{
    const int i = threadIdx.x;
    if (i < NSEC) {
        const int key = ws[i];
        float feat;
        if (key == 0x7fffffff) feat = -1.0f;
        else                   feat = (float)((key & 32767) / WP);
        out[POOLED_SIZE + i] = feat;
    }
}

extern "C" void kernel_launch(void* const* d_in, const int* in_sizes, int n_in,
                              void* d_out, int out_size, void* d_ws, size_t ws_size,
                              hipStream_t stream) {
    const float* x  = (const float*)d_in[0];
    const float* Wg = (const float*)d_in[1];
    float* out = (float*)d_out;
    int*   wsi = (int*)d_ws;
    uint4* wfh = (uint4*)((char*)d_ws + 256);

    const bool pre = ws_size >= 256 + (size_t)NFRAG * 16;   // ~295 KB
    if (pre) {
        prep_kernel<<<dim3(72), dim3(256), 0, stream>>>(Wg, wsi, wfh);
        conv_pool_kernel<true><<<dim3(4320), dim3(256), 0, stream>>>(x, Wg, wfh, out, wsi);
    } else {
        init_kernel<<<dim3(1), dim3(64), 0, stream>>>(wsi);
        conv_pool_kernel<false><<<dim3(4320), dim3(256), 0, stream>>>(x, Wg, wfh, out, wsi);
    }
    finalize_kernel<<<dim3(1), dim3(16), 0, stream>>>(wsi, out);
}